// Round 1
// baseline (551.292 us; speedup 1.0000x reference)
//
#include <hip/hip_runtime.h>

typedef unsigned short u16;
typedef __attribute__((ext_vector_type(8))) short short8;
typedef __attribute__((ext_vector_type(4))) float f32x4;

#define CC 256
#define WW 128
#define HH 128
#define DD 32
#define NN 256
#define WH (WW * HH)
#define PL 2097152       /* elements per q/k plane: G*N*D = 256*256*32 */
#define OUTEL 16777216   /* out tensor elements */

__device__ __forceinline__ u16 f2bf(float f) {
  unsigned u = __float_as_uint(f);
  return (u16)((u + 0x7FFFu + ((u >> 16) & 1u)) >> 16);
}
__device__ __forceinline__ float bf2f(u16 h) {
  return __uint_as_float(((unsigned)h) << 16);
}

// ---------------- K0: pack Wq(32x256) + Wk(32x256) -> wqk[c][64] ----------------
__global__ __launch_bounds__(256) void k_pack(const float* __restrict__ Wq,
                                              const float* __restrict__ Wk,
                                              float* __restrict__ wqk) {
  int idx = blockIdx.x * 256 + threadIdx.x;  // 16384 total
  int r = idx >> 8, c = idx & 255;
  float v = (r < 32) ? Wq[r * 256 + c] : Wk[(r - 32) * 256 + c];
  wqk[c * 64 + r] = v;
}

// ---------------- K1: fp32 q/k projection + hi/lo bf16 split ----------------
// grid 256 (groups), block 512. wave w = d-group (q rows 0-31 for dg<4, k rows for dg>=4)
// outputs: qhi[g][n][d], qlo(+PL), khi(+2PL)[g][m][d], klo(+3PL)   (all bf16)
__global__ __launch_bounds__(512, 2) void k_qk(const float* __restrict__ x,
                                               const float* __restrict__ wqk,
                                               const float* __restrict__ bq,
                                               const float* __restrict__ bk,
                                               u16* __restrict__ qhi) {
  int g = blockIdx.x;
  int bb = g >> 6, wb = (g >> 3) & 7, hb = g & 7;
  int w0 = wb * 16, h0 = hb * 16;
  int t = threadIdx.x, l = t & 63;
  int dg = __builtin_amdgcn_readfirstlane(t >> 6);  // 0..7, wave-uniform
  int dgo = (dg & 3) * 8;                           // d offset within its plane
  const float* xg = x + (size_t)bb * CC * WH + (size_t)(w0 + (l >> 2)) * HH + h0 + ((4 * l) & 15);
  const float* bsrc = (dg < 4) ? bq : bk;
  u16* obase = qhi + (dg < 4 ? 0 : 2 * (size_t)PL);

  float acc[8][4];
#pragma unroll
  for (int j = 0; j < 8; ++j)
#pragma unroll
    for (int i = 0; i < 4; ++i) acc[j][i] = 0.f;

#pragma unroll 2
  for (int c = 0; c < 256; ++c) {
    f32x4 xv = *(const f32x4*)(xg + (size_t)c * WH);
    f32x4 wA = *(const f32x4*)(wqk + c * 64 + dg * 8);
    f32x4 wB = *(const f32x4*)(wqk + c * 64 + dg * 8 + 4);
#pragma unroll
    for (int j = 0; j < 4; ++j)
#pragma unroll
      for (int i = 0; i < 4; ++i) acc[j][i] = fmaf(wA[j], xv[i], acc[j][i]);
#pragma unroll
    for (int j = 0; j < 4; ++j)
#pragma unroll
      for (int i = 0; i < 4; ++i) acc[4 + j][i] = fmaf(wB[j], xv[i], acc[4 + j][i]);
  }

  float bias[8];
#pragma unroll
  for (int j = 0; j < 8; ++j) bias[j] = bsrc[dgo + j];

#pragma unroll
  for (int i = 0; i < 4; ++i) {
    u16 hv[8], lv[8];
#pragma unroll
    for (int j = 0; j < 8; ++j) {
      float v = acc[j][i] + bias[j];
      u16 h = f2bf(v);
      hv[j] = h;
      lv[j] = f2bf(v - bf2f(h));
    }
    int m = 4 * l + i;
    u16* p = obase + (size_t)(g * NN + m) * DD + dgo;
    *(short8*)p = *(short8*)hv;
    *(short8*)(p + PL) = *(short8*)lv;
  }
}

// ---------------- K2: V projection (bf16 MFMA GEMM per group) ----------------
// v_ws[g][c][m] bf16.  LDS: Wv strip [256][32+8], xb strip [256 m][32+8] (transposed)
__global__ __launch_bounds__(512, 2) void k_v(const float* __restrict__ x,
                                              const float* __restrict__ Wv,
                                              const float* __restrict__ bv,
                                              u16* __restrict__ vws) {
  __shared__ u16 wv_lds[256 * 40];
  __shared__ u16 xb_lds[256 * 40];
  int g = blockIdx.x;
  int bb = g >> 6, wb = (g >> 3) & 7, hb = g & 7;
  int w0 = wb * 16, h0 = hb * 16;
  int t = threadIdx.x, l = t & 63, wv = t >> 6;

  f32x4 acc[2][16];
#pragma unroll
  for (int ct = 0; ct < 2; ++ct)
#pragma unroll
    for (int mt = 0; mt < 16; ++mt) acc[ct][mt] = (f32x4){0.f, 0.f, 0.f, 0.f};

  for (int s = 0; s < 8; ++s) {
    int c0 = s * 32;
#pragma unroll
    for (int it = 0; it < 16; ++it) {
      int idx = t + 512 * it;  // 0..8191
      int c = idx >> 5, cc = idx & 31;
      wv_lds[c * 40 + cc] = f2bf(Wv[c * 256 + c0 + cc]);
      int m = idx & 255, sc = idx >> 8;
      xb_lds[m * 40 + sc] =
          f2bf(x[(size_t)(bb * CC + c0 + sc) * WH + (size_t)(w0 + (m >> 4)) * HH + h0 + (m & 15)]);
    }
    __syncthreads();
    short8 a0 = *(const short8*)&wv_lds[(wv * 32 + 0 + (l & 15)) * 40 + (l >> 4) * 8];
    short8 a1 = *(const short8*)&wv_lds[(wv * 32 + 16 + (l & 15)) * 40 + (l >> 4) * 8];
#pragma unroll
    for (int mt = 0; mt < 16; ++mt) {
      short8 b = *(const short8*)&xb_lds[(mt * 16 + (l & 15)) * 40 + (l >> 4) * 8];
      acc[0][mt] = __builtin_amdgcn_mfma_f32_16x16x32_bf16(a0, b, acc[0][mt], 0, 0, 0);
      acc[1][mt] = __builtin_amdgcn_mfma_f32_16x16x32_bf16(a1, b, acc[1][mt], 0, 0, 0);
    }
    __syncthreads();
  }
#pragma unroll
  for (int ct = 0; ct < 2; ++ct)
#pragma unroll
    for (int mt = 0; mt < 16; ++mt)
#pragma unroll
      for (int r = 0; r < 4; ++r) {
        int c = wv * 32 + ct * 16 + (l >> 4) * 4 + r;
        int m = mt * 16 + (l & 15);
        vws[(size_t)(g * CC + c) * NN + m] = f2bf(acc[ct][mt][r] + bv[c]);
      }
}

// ---------------- K3: energy (split-bf16 MFMA) + softmax + PV + residual ----------------
// LDS: att half [128 n][256 m] bf16, 16B-granule XOR swizzled (64 KiB)
__global__ __launch_bounds__(512, 2) void k_attn(const float* __restrict__ x,
                                                 const u16* __restrict__ qhi,
                                                 const u16* __restrict__ khi,
                                                 const u16* __restrict__ vws,
                                                 const float* __restrict__ gamma,
                                                 float* __restrict__ dout) {
  __shared__ u16 att_lds[128 * 256];  // 64 KiB
  int g = blockIdx.x;
  int bb = g >> 6, wb = (g >> 3) & 7, hb = g & 7;
  int w0 = wb * 16, h0 = hb * 16;
  int t = threadIdx.x, l = t & 63, wv = t >> 6;
  float gam = gamma[0];
  float* attg = dout + (size_t)OUTEL;
  char* smem = (char*)att_lds;

  for (int hf = 0; hf < 2; ++hf) {
    int n0 = hf * 128;
    int nt = n0 + wv * 16;

    // ---- energy: e[n][m] for 16 n-rows (this wave) x all 256 m ----
    const u16* qb = qhi + (size_t)(g * NN + nt + (l & 15)) * DD + (l >> 4) * 8;
    short8 ahi = *(const short8*)qb;
    short8 alo = *(const short8*)(qb + PL);
    f32x4 e[16];
#pragma unroll
    for (int mt = 0; mt < 16; ++mt) e[mt] = (f32x4){0.f, 0.f, 0.f, 0.f};
#pragma unroll
    for (int mt = 0; mt < 16; ++mt) {
      const u16* kb = khi + (size_t)(g * NN + mt * 16 + (l & 15)) * DD + (l >> 4) * 8;
      short8 bhi = *(const short8*)kb;
      short8 blo = *(const short8*)(kb + PL);
      e[mt] = __builtin_amdgcn_mfma_f32_16x16x32_bf16(ahi, bhi, e[mt], 0, 0, 0);
      e[mt] = __builtin_amdgcn_mfma_f32_16x16x32_bf16(alo, bhi, e[mt], 0, 0, 0);
      e[mt] = __builtin_amdgcn_mfma_f32_16x16x32_bf16(ahi, blo, e[mt], 0, 0, 0);
    }

    // ---- softmax over m: row n = nt + (l>>4)*4 + r, spread over 16 lanes (l&15) ----
    float inv[4];
#pragma unroll
    for (int r = 0; r < 4; ++r) {
      float m0 = e[0][r];
#pragma unroll
      for (int mt = 1; mt < 16; ++mt) m0 = fmaxf(m0, e[mt][r]);
      m0 = fmaxf(m0, __shfl_xor(m0, 1));
      m0 = fmaxf(m0, __shfl_xor(m0, 2));
      m0 = fmaxf(m0, __shfl_xor(m0, 4));
      m0 = fmaxf(m0, __shfl_xor(m0, 8));
      float s = 0.f;
#pragma unroll
      for (int mt = 0; mt < 16; ++mt) {
        float p = __expf(e[mt][r] - m0);
        e[mt][r] = p;
        s += p;
      }
      s += __shfl_xor(s, 1);
      s += __shfl_xor(s, 2);
      s += __shfl_xor(s, 4);
      s += __shfl_xor(s, 8);
      inv[r] = 1.0f / s;
    }

    // ---- write att: f32 to global output, bf16 (swizzled) to LDS ----
#pragma unroll
    for (int mt = 0; mt < 16; ++mt)
#pragma unroll
      for (int r = 0; r < 4; ++r) {
        int n = nt + (l >> 4) * 4 + r;
        int m = mt * 16 + (l & 15);
        float av = e[mt][r] * inv[r];
        attg[(size_t)(g * NN + n) * NN + m] = av;
        int nn = n - n0;
        int byteoff = nn * 512 + ((2 * m) ^ ((nn & 7) << 4));
        *(u16*)(smem + byteoff) = f2bf(av);
      }
    __syncthreads();

    // ---- PV: out[c][n] = sum_m V[c][m] * att[n][m] ----
    int cbase = (wv >> 1) * 64, nb = (wv & 1) * 64;
    f32x4 o[4][4];
#pragma unroll
    for (int ci = 0; ci < 4; ++ci)
#pragma unroll
      for (int ni = 0; ni < 4; ++ni) o[ci][ni] = (f32x4){0.f, 0.f, 0.f, 0.f};

#pragma unroll
    for (int k = 0; k < 8; ++k) {
      short8 a[4];
#pragma unroll
      for (int ci = 0; ci < 4; ++ci)
        a[ci] = *(const short8*)&vws[(size_t)(g * CC + cbase + ci * 16 + (l & 15)) * NN + k * 32 +
                                     (l >> 4) * 8];
      short8 bf[4];
#pragma unroll
      for (int ni = 0; ni < 4; ++ni) {
        int nn = nb + ni * 16 + (l & 15);
        int byteoff = nn * 512 + ((2 * (k * 32 + (l >> 4) * 8)) ^ ((nn & 7) << 4));
        bf[ni] = *(const short8*)(smem + byteoff);
      }
#pragma unroll
      for (int ci = 0; ci < 4; ++ci)
#pragma unroll
        for (int ni = 0; ni < 4; ++ni)
          o[ci][ni] = __builtin_amdgcn_mfma_f32_16x16x32_bf16(a[ci], bf[ni], o[ci][ni], 0, 0, 0);
    }

    // ---- epilogue: out = gamma*pv + x ----
#pragma unroll
    for (int ci = 0; ci < 4; ++ci)
#pragma unroll
      for (int ni = 0; ni < 4; ++ni)
#pragma unroll
        for (int r = 0; r < 4; ++r) {
          int c = cbase + ci * 16 + (l >> 4) * 4 + r;
          int n = n0 + nb + ni * 16 + (l & 15);
          size_t addr = (size_t)(bb * CC + c) * WH + (size_t)(w0 + (n >> 4)) * HH + h0 + (n & 15);
          dout[addr] = gam * o[ci][ni][r] + x[addr];
        }
    __syncthreads();
  }
}

extern "C" void kernel_launch(void* const* d_in, const int* in_sizes, int n_in,
                              void* d_out, int out_size, void* d_ws, size_t ws_size,
                              hipStream_t stream) {
  const float* x = (const float*)d_in[0];
  const float* Wq = (const float*)d_in[1];
  const float* bq = (const float*)d_in[2];
  const float* Wk = (const float*)d_in[3];
  const float* bk = (const float*)d_in[4];
  const float* Wv = (const float*)d_in[5];
  const float* bv = (const float*)d_in[6];
  const float* gamma = (const float*)d_in[7];
  float* out = (float*)d_out;

  float* wqk = (float*)d_ws;
  u16* qhi = (u16*)((char*)d_ws + 65536);
  u16* khi = qhi + 2 * (size_t)PL;
  u16* vws = qhi + 4 * (size_t)PL;

  k_pack<<<64, 256, 0, stream>>>(Wq, Wk, wqk);
  k_qk<<<256, 512, 0, stream>>>(x, wqk, bq, bk, qhi);
  k_v<<<256, 512, 0, stream>>>(x, Wv, bv, vws);
  k_attn<<<256, 512, 0, stream>>>(x, qhi, khi, vws, gamma, out);
}

// Round 5
// 349.728 us; speedup vs baseline: 1.5763x; 1.5763x over previous
//
#include <hip/hip_runtime.h>

typedef unsigned short u16;
typedef __attribute__((ext_vector_type(8))) short short8;
typedef __attribute__((ext_vector_type(4))) short s16x4;
typedef __attribute__((ext_vector_type(4))) float f32x4;

#define CC 256
#define WW 128
#define HH 128
#define DD 32
#define NN 256
#define WH (WW * HH)
#define P8 524288        /* u16 per d-oct plane: G*N*8 = 256*256*8 */
#define OUTEL 16777216   /* out tensor elements */

__device__ __forceinline__ u16 f2bf(float f) {
  unsigned u = __float_as_uint(f);
  return (u16)((u + 0x7FFFu + ((u >> 16) & 1u)) >> 16);
}
__device__ __forceinline__ float bf2f(u16 h) {
  return __uint_as_float(((unsigned)h) << 16);
}

// ---------------- K0: pack Wq(32x256) + Wk(32x256) -> wqk[c][64] ----------------
__global__ __launch_bounds__(256) void k_pack(const float* __restrict__ Wq,
                                              const float* __restrict__ Wk,
                                              float* __restrict__ wqk) {
  int idx = blockIdx.x * 256 + threadIdx.x;  // 16384 total
  int r = idx >> 8, c = idx & 255;
  float v = (r < 32) ? Wq[r * 256 + c] : Wk[(r - 32) * 256 + c];
  wqk[c * 64 + r] = v;
}

// ---------------- K1: fp32 q/k projection + hi/lo bf16 split ----------------
// grid 256 groups x 1024 thr.  wave dg (0..15): dg<8 -> q d-quad dg*4, else k.
// layout: qk planes of P8 u16: [0..3]=q_hi octs, [4..7]=q_lo, [8..11]=k_hi, [12..15]=k_lo
// plane element: [g][n][8 d-in-oct]
__global__ __launch_bounds__(1024, 2) void k_qk(const float* __restrict__ x,
                                                const float* __restrict__ wqk,
                                                const float* __restrict__ bq,
                                                const float* __restrict__ bk,
                                                u16* __restrict__ qk) {
  int hw = blockIdx.x;
  int g = (hw & 7) * 32 + (hw >> 3);  // XCD-chunked: xcd = g>>5
  int bb = g >> 6, wb = (g >> 3) & 7, hb = g & 7;
  int w0 = wb * 16, h0 = hb * 16;
  int t = threadIdx.x, ln = t & 63;
  int dg = __builtin_amdgcn_readfirstlane(t >> 6);  // 0..15
  int dq4 = dg & 7, is_k = dg >> 3;
  const float* xg = x + (size_t)bb * CC * WH + (size_t)(w0 + (ln >> 2)) * HH + h0 + ((4 * ln) & 15);

  float acc[4][4];
#pragma unroll
  for (int j = 0; j < 4; ++j)
#pragma unroll
    for (int i = 0; i < 4; ++i) acc[j][i] = 0.f;

#pragma unroll 2
  for (int c = 0; c < 256; ++c) {
    f32x4 xv = *(const f32x4*)(xg + (size_t)c * WH);
    f32x4 wv4 = *(const f32x4*)(wqk + c * 64 + dg * 4);
#pragma unroll
    for (int j = 0; j < 4; ++j)
#pragma unroll
      for (int i = 0; i < 4; ++i) acc[j][i] = fmaf(wv4[j], xv[i], acc[j][i]);
  }

  const float* bsrc = is_k ? bk : bq;
  float bias[4];
#pragma unroll
  for (int j = 0; j < 4; ++j) bias[j] = bsrc[dq4 * 4 + j];

  u16* ph = qk + ((size_t)((is_k << 3) + (dq4 >> 1))) * P8;
  int sub = (dq4 & 1) * 4;
#pragma unroll
  for (int i = 0; i < 4; ++i) {
    int m = 4 * ln + i;
    s16x4 hv, lv;
#pragma unroll
    for (int j = 0; j < 4; ++j) {
      float v = acc[j][i] + bias[j];
      u16 h = f2bf(v);
      hv[j] = (short)h;
      lv[j] = (short)f2bf(v - bf2f(h));
    }
    size_t ro = (size_t)(g * NN + m) * 8 + sub;
    *(s16x4*)(ph + ro) = hv;
    *(s16x4*)(ph + 4 * (size_t)P8 + ro) = lv;
  }
}

// ---------------- K2: V projection (bf16 MFMA GEMM), grid 512 = (g, c-half) ----------------
// vws[g][c][m] bf16.  LDS xb[256 m][44] u16 (pad 44: conflict-free b64 frag reads)
__global__ __launch_bounds__(512, 2) void k_v(const float* __restrict__ x,
                                              const float* __restrict__ Wv,
                                              const float* __restrict__ bv,
                                              u16* __restrict__ vws) {
  __shared__ u16 xb[256 * 44];
  int hw = blockIdx.x;
  int L = (hw & 7) * 64 + (hw >> 3);  // xcd = (2g+ch)>>6 = g>>5
  int g = L >> 1, ch = L & 1;
  int bb = g >> 6, wb = (g >> 3) & 7, hb = g & 7;
  int w0 = wb * 16, h0 = hb * 16;
  int t = threadIdx.x, ln = t & 63, wv = t >> 6;
  int cw = wv & 3, mh = wv >> 2;
  int cb = ch * 128 + cw * 32;   // wave's cout base (32 couts)
  int mb = mh * 128;             // wave's m base (128 ms)
  const float* xg = x + (size_t)bb * CC * WH;

  f32x4 acc[2][8];
#pragma unroll
  for (int ci = 0; ci < 2; ++ci)
#pragma unroll
    for (int mt = 0; mt < 8; ++mt) acc[ci][mt] = (f32x4){0.f, 0.f, 0.f, 0.f};

  for (int ks = 0; ks < 8; ++ks) {
    int c0 = ks * 32;
    // stage x[c0..c0+31][0..255] -> xb[m][cl]
    int q = ln >> 4, cl = wv * 4 + q;
#pragma unroll
    for (int it = 0; it < 4; ++it) {
      int mm = it * 64 + 4 * (ln & 15);
      f32x4 xv = *(const f32x4*)(xg + (size_t)(c0 + cl) * WH + (size_t)(w0 + (mm >> 4)) * HH +
                                 h0 + (mm & 15));
#pragma unroll
      for (int j = 0; j < 4; ++j) xb[(mm + j) * 44 + cl] = f2bf(xv[j]);
    }
    __syncthreads();

    // A-frags from global Wv (L1/L2-hot)
    short8 af[2];
#pragma unroll
    for (int ci = 0; ci < 2; ++ci) {
      int row = cb + ci * 16 + (ln & 15);
      const float* wp = Wv + (size_t)row * CC + c0 + (ln >> 4) * 8;
      f32x4 wa = *(const f32x4*)wp;
      f32x4 wb2 = *(const f32x4*)(wp + 4);
#pragma unroll
      for (int j = 0; j < 4; ++j) {
        af[ci][j] = (short)f2bf(wa[j]);
        af[ci][4 + j] = (short)f2bf(wb2[j]);
      }
    }
#pragma unroll
    for (int mt = 0; mt < 8; ++mt) {
      const u16* bp = &xb[(mb + mt * 16 + (ln & 15)) * 44 + (ln >> 4) * 8];
      union { short8 v; s16x4 h[2]; } bu;
      bu.h[0] = *(const s16x4*)bp;
      bu.h[1] = *(const s16x4*)(bp + 4);
#pragma unroll
      for (int ci = 0; ci < 2; ++ci)
        acc[ci][mt] = __builtin_amdgcn_mfma_f32_16x16x32_bf16(af[ci], bu.v, acc[ci][mt], 0, 0, 0);
    }
    __syncthreads();
  }

#pragma unroll
  for (int ci = 0; ci < 2; ++ci)
#pragma unroll
    for (int mt = 0; mt < 8; ++mt)
#pragma unroll
      for (int r = 0; r < 4; ++r) {
        int c = cb + ci * 16 + (ln >> 4) * 4 + r;
        int m = mb + mt * 16 + (ln & 15);
        vws[(size_t)(g * CC + c) * NN + m] = f2bf(acc[ci][mt][r] + bv[c]);
      }
}

// ---------------- K3: energy (split-bf16 MFMA) + softmax + PV + residual ----------------
// grid 512 = (g, n-half).  LDS att [128 n][256 m] bf16, 16B-granule XOR swizzled (64 KiB)
__global__ __launch_bounds__(512, 2) void k_attn(const float* __restrict__ x,
                                                 const u16* __restrict__ qk,
                                                 const u16* __restrict__ vws,
                                                 const float* __restrict__ gamma,
                                                 float* __restrict__ dout) {
  __shared__ u16 att_lds[128 * 256];  // 64 KiB
  int hw = blockIdx.x;
  int L = (hw & 7) * 64 + (hw >> 3);  // xcd = g>>5
  int g = L >> 1, hf = L & 1;
  int bb = g >> 6, wb = (g >> 3) & 7, hb = g & 7;
  int w0 = wb * 16, h0 = hb * 16;
  int t = threadIdx.x, ln = t & 63, wv = t >> 6;
  float gam = gamma[0];
  float* attg = dout + (size_t)OUTEL;
  char* smem = (char*)att_lds;
  int n0 = hf * 128;
  int nt = n0 + wv * 16;
  int oct = ln >> 4;

  // ---- energy: e[n][m] for this wave's 16 n-rows x all 256 m ----
  const u16* qb = qk + (size_t)oct * P8 + (size_t)(g * NN + nt + (ln & 15)) * 8;
  short8 ahi = *(const short8*)qb;
  short8 alo = *(const short8*)(qb + 4 * (size_t)P8);
  f32x4 e[16];
#pragma unroll
  for (int mt = 0; mt < 16; ++mt) e[mt] = (f32x4){0.f, 0.f, 0.f, 0.f};
#pragma unroll
  for (int mt = 0; mt < 16; ++mt) {
    const u16* kb = qk + (size_t)(8 + oct) * P8 + (size_t)(g * NN + mt * 16 + (ln & 15)) * 8;
    short8 bhi = *(const short8*)kb;
    short8 blo = *(const short8*)(kb + 4 * (size_t)P8);
    e[mt] = __builtin_amdgcn_mfma_f32_16x16x32_bf16(ahi, bhi, e[mt], 0, 0, 0);
    e[mt] = __builtin_amdgcn_mfma_f32_16x16x32_bf16(alo, bhi, e[mt], 0, 0, 0);
    e[mt] = __builtin_amdgcn_mfma_f32_16x16x32_bf16(ahi, blo, e[mt], 0, 0, 0);
  }

  // ---- softmax over m: row n = nt + (ln>>4)*4 + r, spread over 16 lanes ----
  float inv[4];
#pragma unroll
  for (int r = 0; r < 4; ++r) {
    float m0 = e[0][r];
#pragma unroll
    for (int mt = 1; mt < 16; ++mt) m0 = fmaxf(m0, e[mt][r]);
    m0 = fmaxf(m0, __shfl_xor(m0, 1));
    m0 = fmaxf(m0, __shfl_xor(m0, 2));
    m0 = fmaxf(m0, __shfl_xor(m0, 4));
    m0 = fmaxf(m0, __shfl_xor(m0, 8));
    float s = 0.f;
#pragma unroll
    for (int mt = 0; mt < 16; ++mt) {
      float p = __expf(e[mt][r] - m0);
      e[mt][r] = p;
      s += p;
    }
    s += __shfl_xor(s, 1);
    s += __shfl_xor(s, 2);
    s += __shfl_xor(s, 4);
    s += __shfl_xor(s, 8);
    inv[r] = 1.0f / s;
  }

  // ---- att -> LDS bf16 (swizzled) ----
#pragma unroll
  for (int mt = 0; mt < 16; ++mt)
#pragma unroll
    for (int r = 0; r < 4; ++r) {
      int nn = wv * 16 + (ln >> 4) * 4 + r;
      int m = mt * 16 + (ln & 15);
      int byteoff = nn * 512 + ((2 * m) ^ ((nn & 7) << 4));
      *(u16*)(smem + byteoff) = f2bf(e[mt][r] * inv[r]);
    }
  __syncthreads();

  // ---- coalesced att writeback: 128 rows x 256 m, float4 full-line stores ----
#pragma unroll
  for (int c = 0; c < 16; ++c) {
    int nn = c * 8 + (t >> 6);
    int m0 = 4 * (t & 63);
    int byteoff = nn * 512 + ((2 * m0) ^ ((nn & 7) << 4));
    s16x4 bv4 = *(const s16x4*)(smem + byteoff);
    f32x4 fv;
#pragma unroll
    for (int j = 0; j < 4; ++j) fv[j] = bf2f((u16)bv4[j]);
    *(f32x4*)(attg + (size_t)(g * NN + n0 + nn) * NN + m0) = fv;
  }

  // ---- PV: out[c][n] = sum_m V[c][m] * att[n][m] ----
  int cbase = (wv >> 1) * 64, nb = (wv & 1) * 64;
  f32x4 o[4][4];
#pragma unroll
  for (int ci = 0; ci < 4; ++ci)
#pragma unroll
    for (int ni = 0; ni < 4; ++ni) o[ci][ni] = (f32x4){0.f, 0.f, 0.f, 0.f};

#pragma unroll
  for (int k = 0; k < 8; ++k) {
    short8 a[4];
#pragma unroll
    for (int ci = 0; ci < 4; ++ci)
      a[ci] = *(const short8*)&vws[(size_t)(g * CC + cbase + ci * 16 + (ln & 15)) * NN + k * 32 +
                                   (ln >> 4) * 8];
    short8 bf[4];
#pragma unroll
    for (int ni = 0; ni < 4; ++ni) {
      int nn = nb + ni * 16 + (ln & 15);
      int byteoff = nn * 512 + ((2 * (k * 32 + (ln >> 4) * 8)) ^ ((nn & 7) << 4));
      bf[ni] = *(const short8*)(smem + byteoff);
    }
#pragma unroll
    for (int ci = 0; ci < 4; ++ci)
#pragma unroll
      for (int ni = 0; ni < 4; ++ni)
        o[ci][ni] = __builtin_amdgcn_mfma_f32_16x16x32_bf16(a[ci], bf[ni], o[ci][ni], 0, 0, 0);
  }

  // ---- epilogue: out = gamma*pv + x ----
#pragma unroll
  for (int ci = 0; ci < 4; ++ci)
#pragma unroll
    for (int ni = 0; ni < 4; ++ni)
#pragma unroll
      for (int r = 0; r < 4; ++r) {
        int c = cbase + ci * 16 + (ln >> 4) * 4 + r;
        int n = n0 + nb + ni * 16 + (ln & 15);
        size_t addr = (size_t)(bb * CC + c) * WH + (size_t)(w0 + (n >> 4)) * HH + h0 + (n & 15);
        dout[addr] = gam * o[ci][ni][r] + x[addr];
      }
}

extern "C" void kernel_launch(void* const* d_in, const int* in_sizes, int n_in,
                              void* d_out, int out_size, void* d_ws, size_t ws_size,
                              hipStream_t stream) {
  const float* x = (const float*)d_in[0];
  const float* Wq = (const float*)d_in[1];
  const float* bq = (const float*)d_in[2];
  const float* Wk = (const float*)d_in[3];
  const float* bk = (const float*)d_in[4];
  const float* Wv = (const float*)d_in[5];
  const float* bv = (const float*)d_in[6];
  const float* gamma = (const float*)d_in[7];
  float* out = (float*)d_out;

  float* wqk = (float*)d_ws;
  u16* qk = (u16*)((char*)d_ws + 65536);
  u16* vws = qk + 16 * (size_t)P8;

  k_pack<<<64, 256, 0, stream>>>(Wq, Wk, wqk);
  k_qk<<<256, 1024, 0, stream>>>(x, wqk, bq, bk, qk);
  k_v<<<512, 512, 0, stream>>>(x, Wv, bv, vws);
  k_attn<<<512, 512, 0, stream>>>(x, qk, vws, gamma, out);
}

// Round 6
// 320.185 us; speedup vs baseline: 1.7218x; 1.0923x over previous
//
#include <hip/hip_runtime.h>

typedef unsigned short u16;
typedef __attribute__((ext_vector_type(8))) short short8;
typedef __attribute__((ext_vector_type(4))) short s16x4;
typedef __attribute__((ext_vector_type(4))) float f32x4;

#define CC 256
#define WW 128
#define HH 128
#define DD 32
#define NN 256
#define WH (WW * HH)
#define P8 524288        /* u16 per d-oct plane: G*N*8 = 256*256*8 */
#define OUTEL 16777216   /* out tensor elements */

__device__ __forceinline__ u16 f2bf(float f) {
  unsigned u = __float_as_uint(f);
  return (u16)((u + 0x7FFFu + ((u >> 16) & 1u)) >> 16);
}
__device__ __forceinline__ float bf2f(u16 h) {
  return __uint_as_float(((unsigned)h) << 16);
}

// ---------------- K0: pack Wq(32x256) + Wk(32x256) -> wqk[c][64] ----------------
__global__ __launch_bounds__(256) void k_pack(const float* __restrict__ Wq,
                                              const float* __restrict__ Wk,
                                              float* __restrict__ wqk) {
  int idx = blockIdx.x * 256 + threadIdx.x;  // 16384 total
  int r = idx >> 8, c = idx & 255;
  float v = (r < 32) ? Wq[r * 256 + c] : Wk[(r - 32) * 256 + c];
  wqk[c * 64 + r] = v;
}

// ---------------- K1: fp32 q/k projection + hi/lo bf16 split ----------------
// grid 256 groups x 1024 thr.  LDS-staged x (double-buffered 64-channel chunks):
// the window is loaded from HBM exactly once per block instead of once per wave.
// wave dg (0..15): dg<8 -> q d-quad dg*4, else k.
// layout: qk planes of P8 u16: [0..3]=q_hi octs, [4..7]=q_lo, [8..11]=k_hi, [12..15]=k_lo
// plane element: [g][n][8 d-in-oct]
__global__ __launch_bounds__(1024) void k_qk(const float* __restrict__ x,
                                             const float* __restrict__ wqk,
                                             const float* __restrict__ bq,
                                             const float* __restrict__ bk,
                                             u16* __restrict__ qk) {
  __shared__ float xs[2][64 * 256];  // 2 x 64 KiB
  int hw = blockIdx.x;
  int g = (hw & 7) * 32 + (hw >> 3);  // XCD-chunked: xcd = g>>5
  int bb = g >> 6, wb = (g >> 3) & 7, hb = g & 7;
  int w0 = wb * 16, h0 = hb * 16;
  int t = threadIdx.x, ln = t & 63;
  int dg = __builtin_amdgcn_readfirstlane(t >> 6);  // 0..15
  int dq4 = dg & 7, is_k = dg >> 3;
  const float* xwin = x + (size_t)bb * CC * WH + (size_t)w0 * HH + h0;

  // staging decomposition: lin = j*1024 + t in [0,4096): c = lin>>6, sub = lin&63
  // global 16B at (c0+c)*WH + (sub>>2)*HH + (sub&3)*4 ; LDS 16B at [c*256 + sub*4]
  f32x4 st[4];
#pragma unroll
  for (int j = 0; j < 4; ++j) {
    int lin = j * 1024 + t;
    int c = lin >> 6, sub = lin & 63;
    st[j] = *(const f32x4*)(xwin + (size_t)c * WH + (sub >> 2) * HH + (sub & 3) * 4);
  }
#pragma unroll
  for (int j = 0; j < 4; ++j) {
    int lin = j * 1024 + t;
    int c = lin >> 6, sub = lin & 63;
    *(f32x4*)&xs[0][c * 256 + sub * 4] = st[j];
  }

  float acc[4][4];
#pragma unroll
  for (int j = 0; j < 4; ++j)
#pragma unroll
    for (int i = 0; i < 4; ++i) acc[j][i] = 0.f;

  for (int s = 0; s < 4; ++s) {
    int nxt = s + 1;
    if (nxt < 4) {  // prefetch next chunk into registers (overlaps with compute)
#pragma unroll
      for (int j = 0; j < 4; ++j) {
        int lin = j * 1024 + t;
        int c = lin >> 6, sub = lin & 63;
        st[j] = *(const f32x4*)(xwin + (size_t)(nxt * 64 + c) * WH + (sub >> 2) * HH +
                                (sub & 3) * 4);
      }
    }
    __syncthreads();  // xs[s&1] fully written
    const float* xb = xs[s & 1];
    const float* wp = wqk + (s * 64) * 64 + dg * 4;
#pragma unroll 4
    for (int cc = 0; cc < 64; ++cc) {
      f32x4 xv = *(const f32x4*)(xb + cc * 256 + 4 * ln);
      f32x4 wv4 = *(const f32x4*)(wp + cc * 64);
#pragma unroll
      for (int j = 0; j < 4; ++j)
#pragma unroll
        for (int i = 0; i < 4; ++i) acc[j][i] = fmaf(wv4[j], xv[i], acc[j][i]);
    }
    if (nxt < 4) {  // write prefetched chunk to the other buffer (no barrier needed: WAR
                    // on xs[nxt&1] is ordered by the barrier at top of this iteration)
#pragma unroll
      for (int j = 0; j < 4; ++j) {
        int lin = j * 1024 + t;
        int c = lin >> 6, sub = lin & 63;
        *(f32x4*)&xs[nxt & 1][c * 256 + sub * 4] = st[j];
      }
    }
  }

  const float* bsrc = is_k ? bk : bq;
  float bias[4];
#pragma unroll
  for (int j = 0; j < 4; ++j) bias[j] = bsrc[dq4 * 4 + j];

  u16* ph = qk + ((size_t)((is_k << 3) + (dq4 >> 1))) * P8;
  int sub = (dq4 & 1) * 4;
#pragma unroll
  for (int i = 0; i < 4; ++i) {
    int m = 4 * ln + i;
    s16x4 hv, lv;
#pragma unroll
    for (int j = 0; j < 4; ++j) {
      float v = acc[j][i] + bias[j];
      u16 h = f2bf(v);
      hv[j] = (short)h;
      lv[j] = (short)f2bf(v - bf2f(h));
    }
    size_t ro = (size_t)(g * NN + m) * 8 + sub;
    *(s16x4*)(ph + ro) = hv;
    *(s16x4*)(ph + 4 * (size_t)P8 + ro) = lv;
  }
}

// ---------------- K2: V projection (bf16 MFMA GEMM), grid 512 = (g, c-half) ----------------
// vws[g][c][m] bf16.  LDS xb[256 m][44] u16 (pad 44: conflict-free b64 frag reads)
__global__ __launch_bounds__(512, 2) void k_v(const float* __restrict__ x,
                                              const float* __restrict__ Wv,
                                              const float* __restrict__ bv,
                                              u16* __restrict__ vws) {
  __shared__ u16 xb[256 * 44];
  int hw = blockIdx.x;
  int L = (hw & 7) * 64 + (hw >> 3);  // xcd = (2g+ch)>>6 = g>>5
  int g = L >> 1, ch = L & 1;
  int bb = g >> 6, wb = (g >> 3) & 7, hb = g & 7;
  int w0 = wb * 16, h0 = hb * 16;
  int t = threadIdx.x, ln = t & 63, wv = t >> 6;
  int cw = wv & 3, mh = wv >> 2;
  int cb = ch * 128 + cw * 32;   // wave's cout base (32 couts)
  int mb = mh * 128;             // wave's m base (128 ms)
  const float* xg = x + (size_t)bb * CC * WH;

  f32x4 acc[2][8];
#pragma unroll
  for (int ci = 0; ci < 2; ++ci)
#pragma unroll
    for (int mt = 0; mt < 8; ++mt) acc[ci][mt] = (f32x4){0.f, 0.f, 0.f, 0.f};

  for (int ks = 0; ks < 8; ++ks) {
    int c0 = ks * 32;
    // stage x[c0..c0+31][0..255] -> xb[m][cl]
    int q = ln >> 4, cl = wv * 4 + q;
#pragma unroll
    for (int it = 0; it < 4; ++it) {
      int mm = it * 64 + 4 * (ln & 15);
      f32x4 xv = *(const f32x4*)(xg + (size_t)(c0 + cl) * WH + (size_t)(w0 + (mm >> 4)) * HH +
                                 h0 + (mm & 15));
#pragma unroll
      for (int j = 0; j < 4; ++j) xb[(mm + j) * 44 + cl] = f2bf(xv[j]);
    }
    __syncthreads();

    // A-frags from global Wv (L1/L2-hot)
    short8 af[2];
#pragma unroll
    for (int ci = 0; ci < 2; ++ci) {
      int row = cb + ci * 16 + (ln & 15);
      const float* wp = Wv + (size_t)row * CC + c0 + (ln >> 4) * 8;
      f32x4 wa = *(const f32x4*)wp;
      f32x4 wb2 = *(const f32x4*)(wp + 4);
#pragma unroll
      for (int j = 0; j < 4; ++j) {
        af[ci][j] = (short)f2bf(wa[j]);
        af[ci][4 + j] = (short)f2bf(wb2[j]);
      }
    }
#pragma unroll
    for (int mt = 0; mt < 8; ++mt) {
      const u16* bp = &xb[(mb + mt * 16 + (ln & 15)) * 44 + (ln >> 4) * 8];
      union { short8 v; s16x4 h[2]; } bu;
      bu.h[0] = *(const s16x4*)bp;
      bu.h[1] = *(const s16x4*)(bp + 4);
#pragma unroll
      for (int ci = 0; ci < 2; ++ci)
        acc[ci][mt] = __builtin_amdgcn_mfma_f32_16x16x32_bf16(af[ci], bu.v, acc[ci][mt], 0, 0, 0);
    }
    __syncthreads();
  }

#pragma unroll
  for (int ci = 0; ci < 2; ++ci)
#pragma unroll
    for (int mt = 0; mt < 8; ++mt)
#pragma unroll
      for (int r = 0; r < 4; ++r) {
        int c = cb + ci * 16 + (ln >> 4) * 4 + r;
        int m = mb + mt * 16 + (ln & 15);
        vws[(size_t)(g * CC + c) * NN + m] = f2bf(acc[ci][mt][r] + bv[c]);
      }
}

// ---------------- K3: energy (split-bf16 MFMA) + softmax + PV + residual ----------------
// grid 512 = (g, n-half).  LDS att [128 n][256 m] bf16, 16B-granule XOR swizzled (64 KiB)
__global__ __launch_bounds__(512, 2) void k_attn(const float* __restrict__ x,
                                                 const u16* __restrict__ qk,
                                                 const u16* __restrict__ vws,
                                                 const float* __restrict__ gamma,
                                                 float* __restrict__ dout) {
  __shared__ u16 att_lds[128 * 256];  // 64 KiB
  int hw = blockIdx.x;
  int L = (hw & 7) * 64 + (hw >> 3);  // xcd = g>>5
  int g = L >> 1, hf = L & 1;
  int bb = g >> 6, wb = (g >> 3) & 7, hb = g & 7;
  int w0 = wb * 16, h0 = hb * 16;
  int t = threadIdx.x, ln = t & 63, wv = t >> 6;
  float gam = gamma[0];
  float* attg = dout + (size_t)OUTEL;
  char* smem = (char*)att_lds;
  int n0 = hf * 128;
  int nt = n0 + wv * 16;
  int oct = ln >> 4;

  // ---- energy: e[n][m] for this wave's 16 n-rows x all 256 m ----
  const u16* qb = qk + (size_t)oct * P8 + (size_t)(g * NN + nt + (ln & 15)) * 8;
  short8 ahi = *(const short8*)qb;
  short8 alo = *(const short8*)(qb + 4 * (size_t)P8);
  f32x4 e[16];
#pragma unroll
  for (int mt = 0; mt < 16; ++mt) e[mt] = (f32x4){0.f, 0.f, 0.f, 0.f};
#pragma unroll
  for (int mt = 0; mt < 16; ++mt) {
    const u16* kb = qk + (size_t)(8 + oct) * P8 + (size_t)(g * NN + mt * 16 + (ln & 15)) * 8;
    short8 bhi = *(const short8*)kb;
    short8 blo = *(const short8*)(kb + 4 * (size_t)P8);
    e[mt] = __builtin_amdgcn_mfma_f32_16x16x32_bf16(ahi, bhi, e[mt], 0, 0, 0);
    e[mt] = __builtin_amdgcn_mfma_f32_16x16x32_bf16(alo, bhi, e[mt], 0, 0, 0);
    e[mt] = __builtin_amdgcn_mfma_f32_16x16x32_bf16(ahi, blo, e[mt], 0, 0, 0);
  }

  // ---- softmax over m: row n = nt + (ln>>4)*4 + r, spread over 16 lanes ----
  float inv[4];
#pragma unroll
  for (int r = 0; r < 4; ++r) {
    float m0 = e[0][r];
#pragma unroll
    for (int mt = 1; mt < 16; ++mt) m0 = fmaxf(m0, e[mt][r]);
    m0 = fmaxf(m0, __shfl_xor(m0, 1));
    m0 = fmaxf(m0, __shfl_xor(m0, 2));
    m0 = fmaxf(m0, __shfl_xor(m0, 4));
    m0 = fmaxf(m0, __shfl_xor(m0, 8));
    float s = 0.f;
#pragma unroll
    for (int mt = 0; mt < 16; ++mt) {
      float p = __expf(e[mt][r] - m0);
      e[mt][r] = p;
      s += p;
    }
    s += __shfl_xor(s, 1);
    s += __shfl_xor(s, 2);
    s += __shfl_xor(s, 4);
    s += __shfl_xor(s, 8);
    inv[r] = 1.0f / s;
  }

  // ---- att -> LDS bf16 (swizzled) ----
#pragma unroll
  for (int mt = 0; mt < 16; ++mt)
#pragma unroll
    for (int r = 0; r < 4; ++r) {
      int nn = wv * 16 + (ln >> 4) * 4 + r;
      int m = mt * 16 + (ln & 15);
      int byteoff = nn * 512 + ((2 * m) ^ ((nn & 7) << 4));
      *(u16*)(smem + byteoff) = f2bf(e[mt][r] * inv[r]);
    }
  __syncthreads();

  // ---- coalesced att writeback: 128 rows x 256 m, float4 full-line stores ----
#pragma unroll
  for (int c = 0; c < 16; ++c) {
    int nn = c * 8 + (t >> 6);
    int m0 = 4 * (t & 63);
    int byteoff = nn * 512 + ((2 * m0) ^ ((nn & 7) << 4));
    s16x4 bv4 = *(const s16x4*)(smem + byteoff);
    f32x4 fv;
#pragma unroll
    for (int j = 0; j < 4; ++j) fv[j] = bf2f((u16)bv4[j]);
    *(f32x4*)(attg + (size_t)(g * NN + n0 + nn) * NN + m0) = fv;
  }

  // ---- PV: out[c][n] = sum_m V[c][m] * att[n][m] ----
  int cbase = (wv >> 1) * 64, nb = (wv & 1) * 64;
  f32x4 o[4][4];
#pragma unroll
  for (int ci = 0; ci < 4; ++ci)
#pragma unroll
    for (int ni = 0; ni < 4; ++ni) o[ci][ni] = (f32x4){0.f, 0.f, 0.f, 0.f};

#pragma unroll
  for (int k = 0; k < 8; ++k) {
    short8 a[4];
#pragma unroll
    for (int ci = 0; ci < 4; ++ci)
      a[ci] = *(const short8*)&vws[(size_t)(g * CC + cbase + ci * 16 + (ln & 15)) * NN + k * 32 +
                                   (ln >> 4) * 8];
    short8 bf[4];
#pragma unroll
    for (int ni = 0; ni < 4; ++ni) {
      int nn = nb + ni * 16 + (ln & 15);
      int byteoff = nn * 512 + ((2 * (k * 32 + (ln >> 4) * 8)) ^ ((nn & 7) << 4));
      bf[ni] = *(const short8*)(smem + byteoff);
    }
#pragma unroll
    for (int ci = 0; ci < 4; ++ci)
#pragma unroll
      for (int ni = 0; ni < 4; ++ni)
        o[ci][ni] = __builtin_amdgcn_mfma_f32_16x16x32_bf16(a[ci], bf[ni], o[ci][ni], 0, 0, 0);
  }

  // ---- epilogue: out = gamma*pv + x ----
#pragma unroll
  for (int ci = 0; ci < 4; ++ci)
#pragma unroll
    for (int ni = 0; ni < 4; ++ni)
#pragma unroll
      for (int r = 0; r < 4; ++r) {
        int c = cbase + ci * 16 + (ln >> 4) * 4 + r;
        int n = n0 + nb + ni * 16 + (ln & 15);
        size_t addr = (size_t)(bb * CC + c) * WH + (size_t)(w0 + (n >> 4)) * HH + h0 + (n & 15);
        dout[addr] = gam * o[ci][ni][r] + x[addr];
      }
}

extern "C" void kernel_launch(void* const* d_in, const int* in_sizes, int n_in,
                              void* d_out, int out_size, void* d_ws, size_t ws_size,
                              hipStream_t stream) {
  const float* x = (const float*)d_in[0];
  const float* Wq = (const float*)d_in[1];
  const float* bq = (const float*)d_in[2];
  const float* Wk = (const float*)d_in[3];
  const float* bk = (const float*)d_in[4];
  const float* Wv = (const float*)d_in[5];
  const float* bv = (const float*)d_in[6];
  const float* gamma = (const float*)d_in[7];
  float* out = (float*)d_out;

  float* wqk = (float*)d_ws;
  u16* qk = (u16*)((char*)d_ws + 65536);
  u16* vws = qk + 16 * (size_t)P8;

  k_pack<<<64, 256, 0, stream>>>(Wq, Wk, wqk);
  k_qk<<<256, 1024, 0, stream>>>(x, wqk, bq, bk, qk);
  k_v<<<512, 512, 0, stream>>>(x, Wv, bv, vws);
  k_attn<<<512, 512, 0, stream>>>(x, qk, vws, gamma, out);
}

// Round 7
// 314.864 us; speedup vs baseline: 1.7509x; 1.0169x over previous
//
#include <hip/hip_runtime.h>

typedef unsigned short u16;
typedef __attribute__((ext_vector_type(8))) short short8;
typedef __attribute__((ext_vector_type(4))) short s16x4;
typedef __attribute__((ext_vector_type(4))) float f32x4;

#define CC 256
#define WW 128
#define HH 128
#define DD 32
#define NN 256
#define WH (WW * HH)
#define P8 524288        /* u16 per d-oct plane: G*N*8 = 256*256*8 */
#define OUTEL 16777216   /* out tensor elements */

__device__ __forceinline__ u16 f2bf(float f) {
  unsigned u = __float_as_uint(f);
  return (u16)((u + 0x7FFFu + ((u >> 16) & 1u)) >> 16);
}
__device__ __forceinline__ float bf2f(u16 h) {
  return __uint_as_float(((unsigned)h) << 16);
}

// ---------------- K0: pack Wq(32x256) + Wk(32x256) -> wqk[c][64] ----------------
__global__ __launch_bounds__(256) void k_pack(const float* __restrict__ Wq,
                                              const float* __restrict__ Wk,
                                              float* __restrict__ wqk) {
  int idx = blockIdx.x * 256 + threadIdx.x;  // 16384 total
  int r = idx >> 8, c = idx & 255;
  float v = (r < 32) ? Wq[r * 256 + c] : Wk[(r - 32) * 256 + c];
  wqk[c * 64 + r] = v;
}

// ---------------- K1: fp32 q/k projection + hi/lo bf16 split ----------------
// grid 256 groups x 1024 thr.  LDS-staged x (double-buffered 64-channel chunks).
// wave dg (0..15): dg<8 -> q d-quad dg*4, else k.
// layout: qk planes of P8 u16: [0..3]=q_hi octs, [4..7]=q_lo, [8..11]=k_hi, [12..15]=k_lo
// plane element: [g][n][8 d-in-oct]
__global__ __launch_bounds__(1024) void k_qk(const float* __restrict__ x,
                                             const float* __restrict__ wqk,
                                             const float* __restrict__ bq,
                                             const float* __restrict__ bk,
                                             u16* __restrict__ qk) {
  __shared__ float xs[2][64 * 256];  // 2 x 64 KiB
  int hw = blockIdx.x;
  int g = (hw & 7) * 32 + (hw >> 3);  // XCD-chunked: xcd = g>>5
  int bb = g >> 6, wb = (g >> 3) & 7, hb = g & 7;
  int w0 = wb * 16, h0 = hb * 16;
  int t = threadIdx.x, ln = t & 63;
  int dg = __builtin_amdgcn_readfirstlane(t >> 6);  // 0..15
  int dq4 = dg & 7, is_k = dg >> 3;
  const float* xwin = x + (size_t)bb * CC * WH + (size_t)w0 * HH + h0;

  // staging decomposition: lin = j*1024 + t in [0,4096): c = lin>>6, sub = lin&63
  f32x4 st[4];
#pragma unroll
  for (int j = 0; j < 4; ++j) {
    int lin = j * 1024 + t;
    int c = lin >> 6, sub = lin & 63;
    st[j] = *(const f32x4*)(xwin + (size_t)c * WH + (sub >> 2) * HH + (sub & 3) * 4);
  }
#pragma unroll
  for (int j = 0; j < 4; ++j) {
    int lin = j * 1024 + t;
    int c = lin >> 6, sub = lin & 63;
    *(f32x4*)&xs[0][c * 256 + sub * 4] = st[j];
  }

  float acc[4][4];
#pragma unroll
  for (int j = 0; j < 4; ++j)
#pragma unroll
    for (int i = 0; i < 4; ++i) acc[j][i] = 0.f;

  for (int s = 0; s < 4; ++s) {
    int nxt = s + 1;
    if (nxt < 4) {
#pragma unroll
      for (int j = 0; j < 4; ++j) {
        int lin = j * 1024 + t;
        int c = lin >> 6, sub = lin & 63;
        st[j] = *(const f32x4*)(xwin + (size_t)(nxt * 64 + c) * WH + (sub >> 2) * HH +
                                (sub & 3) * 4);
      }
    }
    __syncthreads();
    const float* xb = xs[s & 1];
    const float* wp = wqk + (s * 64) * 64 + dg * 4;
#pragma unroll 4
    for (int cc = 0; cc < 64; ++cc) {
      f32x4 xv = *(const f32x4*)(xb + cc * 256 + 4 * ln);
      f32x4 wv4 = *(const f32x4*)(wp + cc * 64);
#pragma unroll
      for (int j = 0; j < 4; ++j)
#pragma unroll
        for (int i = 0; i < 4; ++i) acc[j][i] = fmaf(wv4[j], xv[i], acc[j][i]);
    }
    if (nxt < 4) {
#pragma unroll
      for (int j = 0; j < 4; ++j) {
        int lin = j * 1024 + t;
        int c = lin >> 6, sub = lin & 63;
        *(f32x4*)&xs[nxt & 1][c * 256 + sub * 4] = st[j];
      }
    }
  }

  const float* bsrc = is_k ? bk : bq;
  float bias[4];
#pragma unroll
  for (int j = 0; j < 4; ++j) bias[j] = bsrc[dq4 * 4 + j];

  u16* ph = qk + ((size_t)((is_k << 3) + (dq4 >> 1))) * P8;
  int sub = (dq4 & 1) * 4;
#pragma unroll
  for (int i = 0; i < 4; ++i) {
    int m = 4 * ln + i;
    s16x4 hv, lv;
#pragma unroll
    for (int j = 0; j < 4; ++j) {
      float v = acc[j][i] + bias[j];
      u16 h = f2bf(v);
      hv[j] = (short)h;
      lv[j] = (short)f2bf(v - bf2f(h));
    }
    size_t ro = (size_t)(g * NN + m) * 8 + sub;
    *(s16x4*)(ph + ro) = hv;
    *(s16x4*)(ph + 4 * (size_t)P8 + ro) = lv;
  }
}

// ---------------- K2: V projection (bf16 MFMA GEMM), grid 512 = (g, c-half) ----------------
// vws[g][c][m] bf16.  LDS xb[256 m][44] u16 (pad 44: conflict-free b64 frag reads)
__global__ __launch_bounds__(512, 2) void k_v(const float* __restrict__ x,
                                              const float* __restrict__ Wv,
                                              const float* __restrict__ bv,
                                              u16* __restrict__ vws) {
  __shared__ u16 xb[256 * 44];
  int hw = blockIdx.x;
  int L = (hw & 7) * 64 + (hw >> 3);  // xcd = g>>5
  int g = L >> 1, ch = L & 1;
  int bb = g >> 6, wb = (g >> 3) & 7, hb = g & 7;
  int w0 = wb * 16, h0 = hb * 16;
  int t = threadIdx.x, ln = t & 63, wv = t >> 6;
  int cw = wv & 3, mh = wv >> 2;
  int cb = ch * 128 + cw * 32;   // wave's cout base (32 couts)
  int mb = mh * 128;             // wave's m base (128 ms)
  const float* xg = x + (size_t)bb * CC * WH;

  f32x4 acc[2][8];
#pragma unroll
  for (int ci = 0; ci < 2; ++ci)
#pragma unroll
    for (int mt = 0; mt < 8; ++mt) acc[ci][mt] = (f32x4){0.f, 0.f, 0.f, 0.f};

  for (int ks = 0; ks < 8; ++ks) {
    int c0 = ks * 32;
    // stage x[c0..c0+31][0..255] -> xb[m][cl]
    int q = ln >> 4, cl = wv * 4 + q;
#pragma unroll
    for (int it = 0; it < 4; ++it) {
      int mm = it * 64 + 4 * (ln & 15);
      f32x4 xv = *(const f32x4*)(xg + (size_t)(c0 + cl) * WH + (size_t)(w0 + (mm >> 4)) * HH +
                                 h0 + (mm & 15));
#pragma unroll
      for (int j = 0; j < 4; ++j) xb[(mm + j) * 44 + cl] = f2bf(xv[j]);
    }
    __syncthreads();

    // A-frags from global Wv (L1/L2-hot)
    short8 af[2];
#pragma unroll
    for (int ci = 0; ci < 2; ++ci) {
      int row = cb + ci * 16 + (ln & 15);
      const float* wp = Wv + (size_t)row * CC + c0 + (ln >> 4) * 8;
      f32x4 wa = *(const f32x4*)wp;
      f32x4 wb2 = *(const f32x4*)(wp + 4);
#pragma unroll
      for (int j = 0; j < 4; ++j) {
        af[ci][j] = (short)f2bf(wa[j]);
        af[ci][4 + j] = (short)f2bf(wb2[j]);
      }
    }
#pragma unroll
    for (int mt = 0; mt < 8; ++mt) {
      const u16* bp = &xb[(mb + mt * 16 + (ln & 15)) * 44 + (ln >> 4) * 8];
      union { short8 v; s16x4 h[2]; } bu;
      bu.h[0] = *(const s16x4*)bp;
      bu.h[1] = *(const s16x4*)(bp + 4);
#pragma unroll
      for (int ci = 0; ci < 2; ++ci)
        acc[ci][mt] = __builtin_amdgcn_mfma_f32_16x16x32_bf16(af[ci], bu.v, acc[ci][mt], 0, 0, 0);
    }
    __syncthreads();
  }

#pragma unroll
  for (int ci = 0; ci < 2; ++ci)
#pragma unroll
    for (int mt = 0; mt < 8; ++mt)
#pragma unroll
      for (int r = 0; r < 4; ++r) {
        int c = cb + ci * 16 + (ln >> 4) * 4 + r;
        int m = mb + mt * 16 + (ln & 15);
        vws[(size_t)(g * CC + c) * NN + m] = f2bf(acc[ci][mt][r] + bv[c]);
      }
}

// ---------------- K3: energy (split-bf16 MFMA) + softmax + PV + residual ----------------
// grid 1024 = (g, n-quarter), 256 thr (4 waves).  LDS att [64 n][256 m] bf16,
// 16B-granule XOR swizzled (32 KiB -> 4-5 blocks/CU, whole grid co-resident)
__global__ __launch_bounds__(256, 4) void k_attn(const float* __restrict__ x,
                                                 const u16* __restrict__ qk,
                                                 const u16* __restrict__ vws,
                                                 const float* __restrict__ gamma,
                                                 float* __restrict__ dout) {
  __shared__ u16 att_lds[64 * 256];  // 32 KiB
  int hw = blockIdx.x;
  int L = (hw & 7) * 128 + (hw >> 3);  // xcd = g>>5
  int g = L >> 2, qt = L & 3;
  int bb = g >> 6, wb = (g >> 3) & 7, hb = g & 7;
  int w0 = wb * 16, h0 = hb * 16;
  int t = threadIdx.x, ln = t & 63, wv = t >> 6;  // wv 0..3
  float gam = gamma[0];
  float* attg = dout + (size_t)OUTEL;
  char* smem = (char*)att_lds;
  int n0 = qt * 64;
  int nt = n0 + wv * 16;
  int oct = ln >> 4;

  // ---- energy: e[n][m] for this wave's 16 n-rows x all 256 m ----
  const u16* qb = qk + (size_t)oct * P8 + (size_t)(g * NN + nt + (ln & 15)) * 8;
  short8 ahi = *(const short8*)qb;
  short8 alo = *(const short8*)(qb + 4 * (size_t)P8);
  f32x4 e[16];
#pragma unroll
  for (int mt = 0; mt < 16; ++mt) e[mt] = (f32x4){0.f, 0.f, 0.f, 0.f};
#pragma unroll
  for (int mt = 0; mt < 16; ++mt) {
    const u16* kb = qk + (size_t)(8 + oct) * P8 + (size_t)(g * NN + mt * 16 + (ln & 15)) * 8;
    short8 bhi = *(const short8*)kb;
    short8 blo = *(const short8*)(kb + 4 * (size_t)P8);
    e[mt] = __builtin_amdgcn_mfma_f32_16x16x32_bf16(ahi, bhi, e[mt], 0, 0, 0);
    e[mt] = __builtin_amdgcn_mfma_f32_16x16x32_bf16(alo, bhi, e[mt], 0, 0, 0);
    e[mt] = __builtin_amdgcn_mfma_f32_16x16x32_bf16(ahi, blo, e[mt], 0, 0, 0);
  }

  // ---- softmax over m: row n = nt + (ln>>4)*4 + r, spread over 16 lanes ----
  float inv[4];
#pragma unroll
  for (int r = 0; r < 4; ++r) {
    float m0 = e[0][r];
#pragma unroll
    for (int mt = 1; mt < 16; ++mt) m0 = fmaxf(m0, e[mt][r]);
    m0 = fmaxf(m0, __shfl_xor(m0, 1));
    m0 = fmaxf(m0, __shfl_xor(m0, 2));
    m0 = fmaxf(m0, __shfl_xor(m0, 4));
    m0 = fmaxf(m0, __shfl_xor(m0, 8));
    float s = 0.f;
#pragma unroll
    for (int mt = 0; mt < 16; ++mt) {
      float p = __expf(e[mt][r] - m0);
      e[mt][r] = p;
      s += p;
    }
    s += __shfl_xor(s, 1);
    s += __shfl_xor(s, 2);
    s += __shfl_xor(s, 4);
    s += __shfl_xor(s, 8);
    inv[r] = 1.0f / s;
  }

  // ---- att -> LDS bf16 (swizzled), rows nn = local n (0..63) ----
#pragma unroll
  for (int mt = 0; mt < 16; ++mt)
#pragma unroll
    for (int r = 0; r < 4; ++r) {
      int nn = wv * 16 + (ln >> 4) * 4 + r;
      int m = mt * 16 + (ln & 15);
      int byteoff = nn * 512 + ((2 * m) ^ ((nn & 7) << 4));
      *(u16*)(smem + byteoff) = f2bf(e[mt][r] * inv[r]);
    }
  __syncthreads();

  // ---- coalesced att writeback: 64 rows x 256 m, float4 stores ----
#pragma unroll
  for (int c = 0; c < 16; ++c) {
    int nn = c * 4 + (t >> 6);
    int m0 = 4 * (t & 63);
    int byteoff = nn * 512 + ((2 * m0) ^ ((nn & 7) << 4));
    s16x4 bv4 = *(const s16x4*)(smem + byteoff);
    f32x4 fv;
#pragma unroll
    for (int j = 0; j < 4; ++j) fv[j] = bf2f((u16)bv4[j]);
    *(f32x4*)(attg + (size_t)(g * NN + n0 + nn) * NN + m0) = fv;
  }

  // ---- PV: out[c][n] = sum_m V[c][m] * att[n][m]; wave owns c-range 64 x n-range 64 ----
  int cbase = wv * 64;
  f32x4 o[4][4];
#pragma unroll
  for (int ci = 0; ci < 4; ++ci)
#pragma unroll
    for (int ni = 0; ni < 4; ++ni) o[ci][ni] = (f32x4){0.f, 0.f, 0.f, 0.f};

#pragma unroll
  for (int k = 0; k < 8; ++k) {
    short8 a[4];
#pragma unroll
    for (int ci = 0; ci < 4; ++ci)
      a[ci] = *(const short8*)&vws[(size_t)(g * CC + cbase + ci * 16 + (ln & 15)) * NN + k * 32 +
                                   (ln >> 4) * 8];
    short8 bf[4];
#pragma unroll
    for (int ni = 0; ni < 4; ++ni) {
      int nn = ni * 16 + (ln & 15);
      int byteoff = nn * 512 + ((2 * (k * 32 + (ln >> 4) * 8)) ^ ((nn & 7) << 4));
      bf[ni] = *(const short8*)(smem + byteoff);
    }
#pragma unroll
    for (int ci = 0; ci < 4; ++ci)
#pragma unroll
      for (int ni = 0; ni < 4; ++ni)
        o[ci][ni] = __builtin_amdgcn_mfma_f32_16x16x32_bf16(a[ci], bf[ni], o[ci][ni], 0, 0, 0);
  }

  // ---- epilogue: out = gamma*pv + x ----
#pragma unroll
  for (int ci = 0; ci < 4; ++ci)
#pragma unroll
    for (int ni = 0; ni < 4; ++ni)
#pragma unroll
      for (int r = 0; r < 4; ++r) {
        int c = cbase + ci * 16 + (ln >> 4) * 4 + r;
        int n = n0 + ni * 16 + (ln & 15);
        size_t addr = (size_t)(bb * CC + c) * WH + (size_t)(w0 + (n >> 4)) * HH + h0 + (n & 15);
        dout[addr] = gam * o[ci][ni][r] + x[addr];
      }
}

extern "C" void kernel_launch(void* const* d_in, const int* in_sizes, int n_in,
                              void* d_out, int out_size, void* d_ws, size_t ws_size,
                              hipStream_t stream) {
  const float* x = (const float*)d_in[0];
  const float* Wq = (const float*)d_in[1];
  const float* bq = (const float*)d_in[2];
  const float* Wk = (const float*)d_in[3];
  const float* bk = (const float*)d_in[4];
  const float* Wv = (const float*)d_in[5];
  const float* bv = (const float*)d_in[6];
  const float* gamma = (const float*)d_in[7];
  float* out = (float*)d_out;

  float* wqk = (float*)d_ws;
  u16* qk = (u16*)((char*)d_ws + 65536);
  u16* vws = qk + 16 * (size_t)P8;

  k_pack<<<64, 256, 0, stream>>>(Wq, Wk, wqk);
  k_qk<<<256, 1024, 0, stream>>>(x, wqk, bq, bk, qk);
  k_v<<<512, 512, 0, stream>>>(x, Wv, bv, vws);
  k_attn<<<1024, 256, 0, stream>>>(x, qk, vws, gamma, out);
}

// Round 9
// 292.413 us; speedup vs baseline: 1.8853x; 1.0768x over previous
//
#include <hip/hip_runtime.h>

typedef unsigned short u16;
typedef __attribute__((ext_vector_type(8))) short short8;
typedef __attribute__((ext_vector_type(4))) short s16x4;
typedef __attribute__((ext_vector_type(4))) float f32x4;

#define CC 256
#define WW 128
#define HH 128
#define DD 32
#define NN 256
#define WH (WW * HH)
#define P8 524288        /* u16 per d-oct plane: G*N*8 = 256*256*8 */
#define OUTEL 16777216   /* out tensor elements */

__device__ __forceinline__ u16 f2bf(float f) {
  unsigned u = __float_as_uint(f);
  return (u16)((u + 0x7FFFu + ((u >> 16) & 1u)) >> 16);
}
__device__ __forceinline__ float bf2f(u16 h) {
  return __uint_as_float(((unsigned)h) << 16);
}

// ---------------- K0: pack Wq(32x256) + Wk(32x256) -> wqk[c][64] ----------------
__global__ __launch_bounds__(256) void k_pack(const float* __restrict__ Wq,
                                              const float* __restrict__ Wk,
                                              float* __restrict__ wqk) {
  int idx = blockIdx.x * 256 + threadIdx.x;  // 16384 total
  int r = idx >> 8, c = idx & 255;
  float v = (r < 32) ? Wq[r * 256 + c] : Wk[(r - 32) * 256 + c];
  wqk[c * 64 + r] = v;
}

// ---------------- K1: fp32 q/k projection + hi/lo bf16 split + xbf emit ----------------
// grid 256 groups x 1024 thr.  LDS-staged x (double-buffered 64-channel chunks).
// Also writes xbf[g][cin][m] bf16 (feeds the fused attention's X*att^T GEMM).
__global__ __launch_bounds__(1024) void k_qk(const float* __restrict__ x,
                                             const float* __restrict__ wqk,
                                             const float* __restrict__ bq,
                                             const float* __restrict__ bk,
                                             u16* __restrict__ qk,
                                             u16* __restrict__ xbf) {
  __shared__ float xs[2][64 * 256];  // 2 x 64 KiB
  int hw = blockIdx.x;
  int g = (hw & 7) * 32 + (hw >> 3);  // XCD-chunked: xcd = g>>5
  int bb = g >> 6, wb = (g >> 3) & 7, hb = g & 7;
  int w0 = wb * 16, h0 = hb * 16;
  int t = threadIdx.x, ln = t & 63;
  int dg = __builtin_amdgcn_readfirstlane(t >> 6);  // 0..15
  int dq4 = dg & 7, is_k = dg >> 3;
  const float* xwin = x + (size_t)bb * CC * WH + (size_t)w0 * HH + h0;
  u16* xbg = xbf + (size_t)g * CC * NN;

  // staging decomposition: lin = j*1024 + t in [0,4096): c = lin>>6, sub = lin&63
  f32x4 st[4];
#pragma unroll
  for (int j = 0; j < 4; ++j) {
    int lin = j * 1024 + t;
    int c = lin >> 6, sub = lin & 63;
    st[j] = *(const f32x4*)(xwin + (size_t)c * WH + (sub >> 2) * HH + (sub & 3) * 4);
  }
#pragma unroll
  for (int j = 0; j < 4; ++j) {
    int lin = j * 1024 + t;
    int c = lin >> 6, sub = lin & 63;
    *(f32x4*)&xs[0][c * 256 + sub * 4] = st[j];
    s16x4 bp;
#pragma unroll
    for (int i = 0; i < 4; ++i) bp[i] = (short)f2bf(st[j][i]);
    *(s16x4*)&xbg[(size_t)c * NN + sub * 4] = bp;
  }

  float acc[4][4];
#pragma unroll
  for (int j = 0; j < 4; ++j)
#pragma unroll
    for (int i = 0; i < 4; ++i) acc[j][i] = 0.f;

  for (int s = 0; s < 4; ++s) {
    int nxt = s + 1;
    if (nxt < 4) {
#pragma unroll
      for (int j = 0; j < 4; ++j) {
        int lin = j * 1024 + t;
        int c = lin >> 6, sub = lin & 63;
        st[j] = *(const f32x4*)(xwin + (size_t)(nxt * 64 + c) * WH + (sub >> 2) * HH +
                                (sub & 3) * 4);
      }
    }
    __syncthreads();
    const float* xb = xs[s & 1];
    const float* wp = wqk + (s * 64) * 64 + dg * 4;
#pragma unroll 4
    for (int cc = 0; cc < 64; ++cc) {
      f32x4 xv = *(const f32x4*)(xb + cc * 256 + 4 * ln);
      f32x4 wv4 = *(const f32x4*)(wp + cc * 64);
#pragma unroll
      for (int j = 0; j < 4; ++j)
#pragma unroll
        for (int i = 0; i < 4; ++i) acc[j][i] = fmaf(wv4[j], xv[i], acc[j][i]);
    }
    if (nxt < 4) {
#pragma unroll
      for (int j = 0; j < 4; ++j) {
        int lin = j * 1024 + t;
        int c = lin >> 6, sub = lin & 63;
        *(f32x4*)&xs[nxt & 1][c * 256 + sub * 4] = st[j];
        s16x4 bp;
#pragma unroll
        for (int i = 0; i < 4; ++i) bp[i] = (short)f2bf(st[j][i]);
        *(s16x4*)&xbg[(size_t)(nxt * 64 + c) * NN + sub * 4] = bp;
      }
    }
  }

  const float* bsrc = is_k ? bk : bq;
  float bias[4];
#pragma unroll
  for (int j = 0; j < 4; ++j) bias[j] = bsrc[dq4 * 4 + j];

  u16* ph = qk + ((size_t)((is_k << 3) + (dq4 >> 1))) * P8;
  int sub = (dq4 & 1) * 4;
#pragma unroll
  for (int i = 0; i < 4; ++i) {
    int m = 4 * ln + i;
    s16x4 hv, lv;
#pragma unroll
    for (int j = 0; j < 4; ++j) {
      float v = acc[j][i] + bias[j];
      u16 h = f2bf(v);
      hv[j] = (short)h;
      lv[j] = (short)f2bf(v - bf2f(h));
    }
    size_t ro = (size_t)(g * NN + m) * 8 + sub;
    *(s16x4*)(ph + ro) = hv;
    *(s16x4*)(ph + 4 * (size_t)P8 + ro) = lv;
  }
}

// ---------------- K2: fused energy + softmax + att + out = Wv*(X*att^T) + residual ------
// grid 1024 = (g, n-quarter), 256 thr (4 waves).  LDS 32 KiB tile:
// phase 1: att[64 n][256 m] bf16 (XOR swizzled); phase 2 (same buffer): Y^T[64 n][256 cin]
__global__ __launch_bounds__(256, 4) void k_attn(const float* __restrict__ x,
                                                 const float* __restrict__ Wv,
                                                 const float* __restrict__ bv,
                                                 const u16* __restrict__ qk,
                                                 const u16* __restrict__ xbf,
                                                 const float* __restrict__ gamma,
                                                 float* __restrict__ dout) {
  __shared__ u16 tile[64 * 256];  // 32 KiB
  int hw = blockIdx.x;
  int L = (hw & 7) * 128 + (hw >> 3);  // xcd = g>>5
  int g = L >> 2, qt = L & 3;
  int bb = g >> 6, wb = (g >> 3) & 7, hb = g & 7;
  int w0 = wb * 16, h0 = hb * 16;
  int t = threadIdx.x, ln = t & 63, wv = t >> 6;  // wv 0..3
  float gam = gamma[0];
  float* attg = dout + (size_t)OUTEL;
  char* smem = (char*)tile;
  int n0 = qt * 64;
  int nt = n0 + wv * 16;
  int oct = ln >> 4;

  // ---- energy: e[n][m] for this wave's 16 n-rows x all 256 m ----
  const u16* qb = qk + (size_t)oct * P8 + (size_t)(g * NN + nt + (ln & 15)) * 8;
  short8 ahi = *(const short8*)qb;
  short8 alo = *(const short8*)(qb + 4 * (size_t)P8);
  f32x4 e[16];
#pragma unroll
  for (int mt = 0; mt < 16; ++mt) e[mt] = (f32x4){0.f, 0.f, 0.f, 0.f};
#pragma unroll
  for (int mt = 0; mt < 16; ++mt) {
    const u16* kb = qk + (size_t)(8 + oct) * P8 + (size_t)(g * NN + mt * 16 + (ln & 15)) * 8;
    short8 bhi = *(const short8*)kb;
    short8 blo = *(const short8*)(kb + 4 * (size_t)P8);
    e[mt] = __builtin_amdgcn_mfma_f32_16x16x32_bf16(ahi, bhi, e[mt], 0, 0, 0);
    e[mt] = __builtin_amdgcn_mfma_f32_16x16x32_bf16(alo, bhi, e[mt], 0, 0, 0);
    e[mt] = __builtin_amdgcn_mfma_f32_16x16x32_bf16(ahi, blo, e[mt], 0, 0, 0);
  }

  // ---- softmax over m: row n = nt + (ln>>4)*4 + r, spread over 16 lanes ----
  float inv[4];
#pragma unroll
  for (int r = 0; r < 4; ++r) {
    float m0 = e[0][r];
#pragma unroll
    for (int mt = 1; mt < 16; ++mt) m0 = fmaxf(m0, e[mt][r]);
    m0 = fmaxf(m0, __shfl_xor(m0, 1));
    m0 = fmaxf(m0, __shfl_xor(m0, 2));
    m0 = fmaxf(m0, __shfl_xor(m0, 4));
    m0 = fmaxf(m0, __shfl_xor(m0, 8));
    float s = 0.f;
#pragma unroll
    for (int mt = 0; mt < 16; ++mt) {
      float p = __expf(e[mt][r] - m0);
      e[mt][r] = p;
      s += p;
    }
    s += __shfl_xor(s, 1);
    s += __shfl_xor(s, 2);
    s += __shfl_xor(s, 4);
    s += __shfl_xor(s, 8);
    inv[r] = 1.0f / s;
  }

  // ---- att -> LDS bf16 (swizzled), rows nn = local n (0..63) ----
#pragma unroll
  for (int mt = 0; mt < 16; ++mt)
#pragma unroll
    for (int r = 0; r < 4; ++r) {
      int nn = wv * 16 + (ln >> 4) * 4 + r;
      int m = mt * 16 + (ln & 15);
      int byteoff = nn * 512 + ((2 * m) ^ ((nn & 7) << 4));
      *(u16*)(smem + byteoff) = f2bf(e[mt][r] * inv[r]);
    }
  __syncthreads();

  // ---- coalesced att writeback: 64 rows x 256 m, float4 stores ----
#pragma unroll
  for (int c = 0; c < 16; ++c) {
    int nn = c * 4 + (t >> 6);
    int m0 = 4 * (t & 63);
    int byteoff = nn * 512 + ((2 * m0) ^ ((nn & 7) << 4));
    s16x4 bv4 = *(const s16x4*)(smem + byteoff);
    f32x4 fv;
#pragma unroll
    for (int j = 0; j < 4; ++j) fv[j] = bf2f((u16)bv4[j]);
    *(f32x4*)(attg + (size_t)(g * NN + n0 + nn) * NN + m0) = fv;
  }

  // ---- GEMM1: Y[cin][n] = sum_m xbf[cin][m] * att[n][m]; wave owns cin-64 x n-64 ----
  int cbase = wv * 64;
  const u16* xbg = xbf + (size_t)g * CC * NN;
  f32x4 y[4][4];
#pragma unroll
  for (int ci = 0; ci < 4; ++ci)
#pragma unroll
    for (int ni = 0; ni < 4; ++ni) y[ci][ni] = (f32x4){0.f, 0.f, 0.f, 0.f};

#pragma unroll
  for (int kk = 0; kk < 8; ++kk) {
    short8 a[4];
#pragma unroll
    for (int ci = 0; ci < 4; ++ci)
      a[ci] = *(const short8*)&xbg[(size_t)(cbase + ci * 16 + (ln & 15)) * NN + kk * 32 +
                                   (ln >> 4) * 8];
    short8 bf[4];
#pragma unroll
    for (int ni = 0; ni < 4; ++ni) {
      int nn = ni * 16 + (ln & 15);
      int byteoff = nn * 512 + ((2 * (kk * 32 + (ln >> 4) * 8)) ^ ((nn & 7) << 4));
      bf[ni] = *(const short8*)(smem + byteoff);
    }
#pragma unroll
    for (int ci = 0; ci < 4; ++ci)
#pragma unroll
      for (int ni = 0; ni < 4; ++ni)
        y[ci][ni] = __builtin_amdgcn_mfma_f32_16x16x32_bf16(a[ci], bf[ni], y[ci][ni], 0, 0, 0);
  }
  __syncthreads();  // everyone done READING att from the tile

  // ---- Y^T -> LDS bf16 (same buffer, same swizzle): Yl[n 0..63][cin 0..255] ----
#pragma unroll
  for (int ci = 0; ci < 4; ++ci)
#pragma unroll
    for (int ni = 0; ni < 4; ++ni)
#pragma unroll
      for (int r = 0; r < 4; ++r) {
        int nn = ni * 16 + (ln & 15);
        int cin = cbase + ci * 16 + (ln >> 4) * 4 + r;
        int byteoff = nn * 512 + ((2 * cin) ^ ((nn & 7) << 4));
        *(u16*)(smem + byteoff) = f2bf(y[ci][ni][r]);
      }
  __syncthreads();

  // ---- GEMM2: out[c][n] = sum_cin Wv[c][cin] * Y[cin][n]; wave owns c-64 x n-64 ----
  f32x4 o[4][4];
#pragma unroll
  for (int ci = 0; ci < 4; ++ci)
#pragma unroll
    for (int ni = 0; ni < 4; ++ni) o[ci][ni] = (f32x4){0.f, 0.f, 0.f, 0.f};

#pragma unroll
  for (int kk = 0; kk < 8; ++kk) {
    short8 wf[4];
#pragma unroll
    for (int ci = 0; ci < 4; ++ci) {
      int row = cbase + ci * 16 + (ln & 15);
      const float* wp = Wv + (size_t)row * CC + kk * 32 + (ln >> 4) * 8;
      f32x4 wa = *(const f32x4*)wp;
      f32x4 wb2 = *(const f32x4*)(wp + 4);
#pragma unroll
      for (int j = 0; j < 4; ++j) {
        wf[ci][j] = (short)f2bf(wa[j]);
        wf[ci][4 + j] = (short)f2bf(wb2[j]);
      }
    }
    short8 bf[4];
#pragma unroll
    for (int ni = 0; ni < 4; ++ni) {
      int nn = ni * 16 + (ln & 15);
      int byteoff = nn * 512 + ((2 * (kk * 32 + (ln >> 4) * 8)) ^ ((nn & 7) << 4));
      bf[ni] = *(const short8*)(smem + byteoff);
    }
#pragma unroll
    for (int ci = 0; ci < 4; ++ci)
#pragma unroll
      for (int ni = 0; ni < 4; ++ni)
        o[ci][ni] = __builtin_amdgcn_mfma_f32_16x16x32_bf16(wf[ci], bf[ni], o[ci][ni], 0, 0, 0);
  }

  // ---- epilogue: out = gamma*(pv + bv) + x ----
#pragma unroll
  for (int ci = 0; ci < 4; ++ci) {
    f32x4 bvv = *(const f32x4*)(bv + cbase + ci * 16 + (ln >> 4) * 4);
#pragma unroll
    for (int ni = 0; ni < 4; ++ni)
#pragma unroll
      for (int r = 0; r < 4; ++r) {
        int c = cbase + ci * 16 + (ln >> 4) * 4 + r;
        int n = n0 + ni * 16 + (ln & 15);
        size_t addr = (size_t)(bb * CC + c) * WH + (size_t)(w0 + (n >> 4)) * HH + h0 + (n & 15);
        dout[addr] = gam * (o[ci][ni][r] + bvv[r]) + x[addr];
      }
  }
}

extern "C" void kernel_launch(void* const* d_in, const int* in_sizes, int n_in,
                              void* d_out, int out_size, void* d_ws, size_t ws_size,
                              hipStream_t stream) {
  const float* x = (const float*)d_in[0];
  const float* Wq = (const float*)d_in[1];
  const float* bq = (const float*)d_in[2];
  const float* Wk = (const float*)d_in[3];
  const float* bk = (const float*)d_in[4];
  const float* Wv = (const float*)d_in[5];
  const float* bv = (const float*)d_in[6];
  const float* gamma = (const float*)d_in[7];
  float* out = (float*)d_out;

  float* wqk = (float*)d_ws;
  u16* qk = (u16*)((char*)d_ws + 65536);
  u16* xbf = qk + 16 * (size_t)P8;  // 32 MB, replaces old vws slot

  k_pack<<<64, 256, 0, stream>>>(Wq, Wk, wqk);
  k_qk<<<256, 1024, 0, stream>>>(x, wqk, bq, bk, qk, xbf);
  k_attn<<<1024, 256, 0, stream>>>(x, Wv, bv, qk, xbf, gamma, out);
}